// Round 3
// baseline (205.174 us; speedup 1.0000x reference)
//
#include <hip/hip_runtime.h>
#include <hip/hip_fp16.h>

#define DIM 128
#define KK 3
#define RPB 16       // rows per fused block (one MFMA M-tile)
#define ZPAD 392     // zs row stride in shorts
#define NSH 8        // shards per row = XCD count
#define CAP 8        // slots per (row,shard): one 64B line
#define CAPR 40      // per-row LDS queue capacity (deg ~ Poisson(16))
#define OVF_CAP 65536

typedef __attribute__((ext_vector_type(4))) float f32x4;
typedef __attribute__((ext_vector_type(8))) short bf16x8;

__device__ __forceinline__ unsigned pkbf(float lo, float hi) {
    unsigned a = __float_as_uint(lo), b = __float_as_uint(hi);
    a = (a + 0x7fffu + ((a >> 16) & 1u)) >> 16;
    b = (b + 0x7fffu + ((b >> 16) & 1u)) & 0xffff0000u;
    return (a & 0xffffu) | b;
}

// ---------- K1a: xcast + W B-fragments (streaming, no scatter) ----------
__global__ __launch_bounds__(256) void k1a_kernel(
        const float* __restrict__ x, const float* __restrict__ w,
        uint2* __restrict__ xb2q, bf16x8* __restrict__ wbf,
        int xq_total, int xblk) {
    int b = blockIdx.x;
    if (b < xblk) {
        int i = b * 256 + threadIdx.x;
        if (i < xq_total) {
            float4 v = ((const float4*)x)[i];
            xb2q[i] = make_uint2(pkbf(v.x, v.y), pkbf(v.z, v.w));
        }
    } else {
        int t = (b - xblk) * 256 + threadIdx.x;
        if (t < 12 * 8 * 64) {
            int lane = t & 63;
            int quad = lane >> 4;
            int nn = ((t >> 6) & 7) * 16 + (lane & 15);
            int kbase = (t >> 9) * 32 + quad * 8;
            short vals[8];
#pragma unroll
            for (int j = 0; j < 8; ++j) {
                int k = kbase + j;
                int k3 = k >> 7, i2 = k & (DIM - 1);
                unsigned bv = __float_as_uint(w[((size_t)i2 * DIM + nn) * KK + k3]);
                vals[j] = (short)((bv + 0x7fffu + ((bv >> 16) & 1u)) >> 16);
            }
            wbf[t] = *(const bf16x8*)vals;
        }
    }
}

// ---------- K1b: per-(row,shard) binned edge fill ----------
// Shard-major: cnt[s*n+row], rec8[(s*n+row)*CAP+pos]; s = this block's XCD,
// so counter atomics run in the XCD-local L2 (wg scope).
// rec8 stores are NON-TEMPORAL: 8B payloads to never-read-before-write lines.
// nt skips the 64B write-allocate line fill (the suspected hidden read per
// store) and streams masked writes out without polluting L2.
__global__ __launch_bounds__(256) void k1b_kernel(
        const float* __restrict__ TT, const int* __restrict__ eidx,
        int* __restrict__ cnt, unsigned long long* __restrict__ rec8,
        int* __restrict__ ovf_cnt, uint4* __restrict__ ovf,
        int E, int n) {
    __shared__ float tts[768];
    int e0 = blockIdx.x * 256;
    int i4 = threadIdx.x;
    if (i4 < 192 && (e0 * 3 + i4 * 4) < E * 3 - 3)
        *(float4*)&tts[i4 * 4] = ((const float4*)(TT + (size_t)e0 * 3))[i4];
    unsigned xcc;
    asm("s_getreg_b32 %0, hwreg(HW_REG_XCC_ID)" : "=s"(xcc));
    int s = (int)(xcc & (NSH - 1));
    __syncthreads();
    int e = e0 + threadIdx.x;
    if (e < E) {
        int row = eidx[e];
        int col = eidx[(size_t)E + e];
        unsigned h0 = __half_as_ushort(__float2half_rn(tts[threadIdx.x * 3 + 0]));
        unsigned h1 = __half_as_ushort(__float2half_rn(tts[threadIdx.x * 3 + 1]));
        unsigned h2 = __half_as_ushort(__float2half_rn(tts[threadIdx.x * 3 + 2]));
        int pos = __hip_atomic_fetch_add(&cnt[(size_t)s * n + row], 1,
                                         __ATOMIC_RELAXED,
                                         __HIP_MEMORY_SCOPE_WORKGROUP);
        if (pos < CAP) {
            unsigned long long rec =
                (unsigned long long)((unsigned)col | (h0 << 16)) |
                ((unsigned long long)(h1 | (h2 << 16)) << 32);
            __builtin_nontemporal_store(rec, &rec8[((size_t)s * n + row) * CAP + pos]);
        } else {
            int op = atomicAdd(ovf_cnt, 1);  // rare: device scope is fine
            if (op < OVF_CAP)
                ovf[op] = make_uint4((unsigned)col, h0 | (h1 << 16), h2, (unsigned)row);
        }
    }
}

// ---------- K2: fused LDS-compacted aggregate + MFMA gemm ----------
__device__ __forceinline__ void edge_fma(uint2 rc, const unsigned* __restrict__ xb2, int lane,
        float& a0l, float& a0h, float& a1l, float& a1h, float& a2l, float& a2h) {
    int c = rc.x & 0xffffu;
    float t0 = __half2float(__ushort_as_half((unsigned short)(rc.x >> 16)));
    float t1 = __half2float(__ushort_as_half((unsigned short)(rc.y & 0xffffu)));
    float t2 = __half2float(__ushort_as_half((unsigned short)(rc.y >> 16)));
    unsigned u = xb2[(size_t)c * 64 + lane];
    float xl = __uint_as_float(u << 16), xh = __uint_as_float(u & 0xffff0000u);
    a0l = fmaf(t0, xl, a0l); a0h = fmaf(t0, xh, a0h);
    a1l = fmaf(t1, xl, a1l); a1h = fmaf(t1, xh, a1h);
    a2l = fmaf(t2, xl, a2l); a2h = fmaf(t2, xh, a2h);
}

__global__ __launch_bounds__(256) void fused_kernel(const unsigned long long* __restrict__ rec8,
        const int* __restrict__ cnt, const unsigned* __restrict__ xb2,
        const bf16x8* __restrict__ wbf, const float* __restrict__ bias,
        float* __restrict__ out, int* __restrict__ ovf_cnt, uint4* __restrict__ ovf,
        int n) {
    __shared__ short zs16[RPB][ZPAD];
    __shared__ uint2 q[RPB][CAPR];
    __shared__ int qc[RPB];
    __shared__ int cc[RPB * NSH];
    int tid = threadIdx.x;
    int lane = tid & 63, wv = tid >> 6;
    int n0 = blockIdx.x * RPB;

    if (tid < RPB) qc[tid] = 0;
    if (tid < RPB * NSH) {
        int rl = tid & 15, s = tid >> 4;
        int r = n0 + rl;
        cc[rl * NSH + s] = (r < n) ? min(cnt[(size_t)s * n + r], CAP) : 0;
    }
    __syncthreads();

    // stage: stream 1024 slots coalesced, compact into per-row LDS queues.
    // shard-major decode: slot = s*128 + rl*8 + p. nt loads: read-once data.
#pragma unroll
    for (int pass = 0; pass < 4; ++pass) {
        int slot = pass * 256 + tid;
        int s = slot >> 7, rl = (slot >> 3) & 15, p = slot & 7;
        if (p < cc[rl * NSH + s]) {
            unsigned long long rv =
                __builtin_nontemporal_load(&rec8[((size_t)s * n + (n0 + rl)) * CAP + p]);
            uint2 rr = make_uint2((unsigned)rv, (unsigned)(rv >> 32));
            int pos = atomicAdd(&qc[rl], 1);  // native LDS int atomic
            if (pos < CAPR) q[rl][pos] = rr;
            else {
                int op = atomicAdd(ovf_cnt, 1);
                if (op < OVF_CAP)
                    ovf[op] = make_uint4(rr.x & 0xffffu,
                                         (rr.x >> 16) | ((rr.y & 0xffffu) << 16),
                                         rr.y >> 16, (unsigned)(n0 + rl));
            }
        }
    }
    __syncthreads();

    // aggregate: wave wv handles rows wv*4 .. wv*4+3, records from LDS
#pragma unroll
    for (int ii = 0; ii < 4; ++ii) {
        int rl = wv * 4 + ii;
        float a0l = 0, a0h = 0, a1l = 0, a1h = 0, a2l = 0, a2h = 0;
        int c = min(qc[rl], CAPR);
        int p = 0;
        for (; p + 4 <= c; p += 4) {
            uint2 r0 = q[rl][p], r1 = q[rl][p + 1], r2 = q[rl][p + 2], r3 = q[rl][p + 3];
            edge_fma(r0, xb2, lane, a0l, a0h, a1l, a1h, a2l, a2h);
            edge_fma(r1, xb2, lane, a0l, a0h, a1l, a1h, a2l, a2h);
            edge_fma(r2, xb2, lane, a0l, a0h, a1l, a1h, a2l, a2h);
            edge_fma(r3, xb2, lane, a0l, a0h, a1l, a1h, a2l, a2h);
        }
        for (; p < c; ++p)
            edge_fma(q[rl][p], xb2, lane, a0l, a0h, a1l, a1h, a2l, a2h);
        *(unsigned*)&zs16[rl][0 * DIM + 2 * lane] = pkbf(a0l, a0h);
        *(unsigned*)&zs16[rl][1 * DIM + 2 * lane] = pkbf(a1l, a1h);
        *(unsigned*)&zs16[rl][2 * DIM + 2 * lane] = pkbf(a2l, a2h);
    }
    __syncthreads();

    // MFMA: M=16 rows, N=128 (2 x 16-tiles per wave), K=384 (12 steps)
    int quad = lane >> 4, m = lane & 15;
    int nt0 = wv * 2, nt1 = wv * 2 + 1;
    f32x4 acc0 = {0.f, 0.f, 0.f, 0.f}, acc1 = {0.f, 0.f, 0.f, 0.f};
#pragma unroll
    for (int kt = 0; kt < 12; ++kt) {
        bf16x8 a  = *(const bf16x8*)&zs16[m][kt * 32 + quad * 8];
        bf16x8 b0 = wbf[(kt * 8 + nt0) * 64 + lane];
        bf16x8 b1 = wbf[(kt * 8 + nt1) * 64 + lane];
        acc0 = __builtin_amdgcn_mfma_f32_16x16x32_bf16(a, b0, acc0, 0, 0, 0);
        acc1 = __builtin_amdgcn_mfma_f32_16x16x32_bf16(a, b1, acc1, 0, 0, 0);
    }
    // C/D layout: col(n)=lane&15, row(m)=quad*4+reg  [m89-verified]
    float bi0 = bias[nt0 * 16 + m], bi1 = bias[nt1 * 16 + m];
#pragma unroll
    for (int rr = 0; rr < 4; ++rr) {
        int node = n0 + quad * 4 + rr;
        if (node < n) {
            out[(size_t)node * DIM + nt0 * 16 + m] = acc0[rr] + bi0;
            out[(size_t)node * DIM + nt1 * 16 + m] = acc1[rr] + bi1;
        }
    }
}

// ---------- K3: exact replay of overflow edges (expected ~100 edges) ----------
__global__ __launch_bounds__(128) void ovf_kernel(const uint4* __restrict__ ovf,
        const int* __restrict__ ovf_cnt, const float* __restrict__ x,
        const float* __restrict__ w, float* __restrict__ out) {
    int total = min(*ovf_cnt, OVF_CAP);
    int d = threadIdx.x;
    for (int i = blockIdx.x; i < total; i += gridDim.x) {
        uint4 r = ovf[i];
        int col = (int)r.x, row = (int)r.w;
        float t0 = __half2float(__ushort_as_half((unsigned short)(r.y & 0xffffu)));
        float t1 = __half2float(__ushort_as_half((unsigned short)(r.y >> 16)));
        float t2 = __half2float(__ushort_as_half((unsigned short)(r.z & 0xffffu)));
        float acc = 0.f;
        for (int ii = 0; ii < DIM; ++ii) {
            const float* wp = &w[((size_t)ii * DIM + d) * KK];
            acc = fmaf(x[(size_t)col * DIM + ii],
                       t0 * wp[0] + t1 * wp[1] + t2 * wp[2], acc);
        }
        atomicAdd(&out[(size_t)row * DIM + d], acc);
    }
}

extern "C" void kernel_launch(void* const* d_in, const int* in_sizes, int n_in,
                              void* d_out, int out_size, void* d_ws, size_t ws_size,
                              hipStream_t stream) {
    const float* x    = (const float*)d_in[0];
    const float* TT   = (const float*)d_in[1];
    const float* w    = (const float*)d_in[2];
    const float* bias = (const float*)d_in[3];
    const int*   eidx = (const int*)d_in[4];
    float* out = (float*)d_out;

    int n = in_sizes[0] / DIM;     // 50000 (< 65536: col packs in 16 bits)
    int E = in_sizes[1] / KK;      // 800000
    int ncell = n * NSH;           // 400000 (row,shard) cells

    char* ws = (char*)d_ws;
    size_t o = 0;
    auto take = [&](size_t b) { void* p = ws + o; o += (b + 255) & ~(size_t)255; return p; };
    unsigned long long* rec8 = (unsigned long long*)take((size_t)ncell * CAP * 8);
    int*      cnt  = (int*)take((size_t)(ncell + 64) * 4);   // counters + ovf_cnt
    uint4*    ovf  = (uint4*)take((size_t)OVF_CAP * 16);
    bf16x8*   wbf  = (bf16x8*)take((size_t)12 * 8 * 64 * 16);
    unsigned* xb2  = (unsigned*)take((size_t)n * DIM * 2);
    (void)ws_size;
    int* ovf_cnt = cnt + ncell;

    hipMemsetAsync(cnt, 0, (size_t)(ncell + 64) * 4, stream);

    int xq = n * DIM / 4;
    int xblk = (xq + 255) / 256;          // 6250
    int eblk = (E + 255) / 256;           // 3125

    k1a_kernel<<<xblk + 24, 256, 0, stream>>>(x, w, (uint2*)xb2, wbf, xq, xblk);
    k1b_kernel<<<eblk, 256, 0, stream>>>(TT, eidx, cnt, rec8, ovf_cnt, ovf, E, n);
    fused_kernel<<<(n + RPB - 1) / RPB, 256, 0, stream>>>(
        rec8, cnt, xb2, wbf, bias, out, ovf_cnt, ovf, n);
    ovf_kernel<<<64, 128, 0, stream>>>(ovf, ovf_cnt, x, w, out);
}

// Round 4
// 158.639 us; speedup vs baseline: 1.2933x; 1.2933x over previous
//
#include <hip/hip_runtime.h>
#include <hip/hip_fp16.h>

#define DIM 128
#define KK 3
#define RPB 16       // rows per fused block (one MFMA M-tile)
#define ZPAD 392     // zs row stride in shorts
#define EBLK 4096    // edges per pass-A block
#define NBKT 256     // coarse bucket space (row>>8); 196 used at n=50000
#define CAPB 5120    // records per bucket region (mean 4082, +16 sigma)
#define QF   1024    // K2 LDS stream chunk (records)
#define OVF_CAP 65536

typedef __attribute__((ext_vector_type(4))) float f32x4;
typedef __attribute__((ext_vector_type(8))) short bf16x8;

__device__ __forceinline__ unsigned pkbf(float lo, float hi) {
    unsigned a = __float_as_uint(lo), b = __float_as_uint(hi);
    a = (a + 0x7fffu + ((a >> 16) & 1u)) >> 16;
    b = (b + 0x7fffu + ((b >> 16) & 1u)) & 0xffff0000u;
    return (a & 0xffffu) | b;
}

// ---------- K1a: xcast + W B-fragments (streaming, no scatter) ----------
__global__ __launch_bounds__(256) void k1a_kernel(
        const float* __restrict__ x, const float* __restrict__ w,
        uint2* __restrict__ xb2q, bf16x8* __restrict__ wbf,
        int xq_total, int xblk) {
    int b = blockIdx.x;
    if (b < xblk) {
        int i = b * 256 + threadIdx.x;
        if (i < xq_total) {
            float4 v = ((const float4*)x)[i];
            xb2q[i] = make_uint2(pkbf(v.x, v.y), pkbf(v.z, v.w));
        }
    } else {
        int t = (b - xblk) * 256 + threadIdx.x;
        if (t < 12 * 8 * 64) {
            int lane = t & 63;
            int quad = lane >> 4;
            int nn = ((t >> 6) & 7) * 16 + (lane & 15);
            int kbase = (t >> 9) * 32 + quad * 8;
            short vals[8];
#pragma unroll
            for (int j = 0; j < 8; ++j) {
                int k = kbase + j;
                int k3 = k >> 7, i2 = k & (DIM - 1);
                unsigned bv = __float_as_uint(w[((size_t)i2 * DIM + nn) * KK + k3]);
                vals[j] = (short)((bv + 0x7fffu + ((bv >> 16) & 1u)) >> 16);
            }
            wbf[t] = *(const bf16x8*)vals;
        }
    }
}

// ---------- Pass A: LDS multisplit by coarse bucket (row>>8) ----------
// Replaces 800k scattered global atomics+8B stores with: 800k LDS atomics,
// 50k global atomics (one per block x bucket), and ~192B semi-coalesced runs.
__global__ __launch_bounds__(1024) void binA_kernel(
        const float* __restrict__ TT, const int* __restrict__ eidx,
        int* __restrict__ bucketCnt, uint4* __restrict__ rec16,
        int* __restrict__ ovf_cnt, uint4* __restrict__ ovf, int E) {
    __shared__ unsigned sw0[EBLK], sw1[EBLK], sw2[EBLK];   // 48KB staging
    __shared__ int hist[NBKT], scn[NBKT], cursor[NBKT], gbase[NBKT];
    int tid = threadIdx.x, blk = blockIdx.x;
    int e0 = blk * EBLK;
    int nval = min(EBLK, E - e0);

    if (tid < NBKT) hist[tid] = 0;
    __syncthreads();

    // phase 1: load 4 edges/thread, histogram coarse bucket
    unsigned w0v[4], w1v[4], w2v[4];
    int bv[4];
#pragma unroll
    for (int i = 0; i < 4; ++i) {
        int li = tid + i * 1024;
        bv[i] = -1;
        if (li < nval) {
            int e = e0 + li;
            int row = eidx[e];
            int col = eidx[(size_t)E + e];
            unsigned h0 = __half_as_ushort(__float2half_rn(TT[(size_t)e * 3 + 0]));
            unsigned h1 = __half_as_ushort(__float2half_rn(TT[(size_t)e * 3 + 1]));
            unsigned h2 = __half_as_ushort(__float2half_rn(TT[(size_t)e * 3 + 2]));
            w0v[i] = (unsigned)col | ((unsigned)row << 16);
            w1v[i] = h0 | (h1 << 16);
            w2v[i] = h2;
            bv[i] = row >> 8;
            atomicAdd(&hist[bv[i]], 1);
        }
    }
    __syncthreads();

    // phase 2: exclusive scan over 256 bucket counts (Hillis-Steele)
    if (tid < NBKT) scn[tid] = hist[tid];
    __syncthreads();
    for (int d = 1; d < NBKT; d <<= 1) {
        int v = 0;
        if (tid < NBKT && tid >= d) v = scn[tid - d];
        __syncthreads();
        if (tid < NBKT && tid >= d) scn[tid] += v;
        __syncthreads();
    }
    if (tid < NBKT) {
        int ex = scn[tid] - hist[tid];
        scn[tid] = ex;
        cursor[tid] = ex;
        gbase[tid] = atomicAdd(&bucketCnt[tid], hist[tid]);  // 1 atomic/bucket
    }
    __syncthreads();

    // phase 3: scatter records into LDS, bucket-sorted
#pragma unroll
    for (int i = 0; i < 4; ++i) {
        if (bv[i] >= 0) {
            int lpos = atomicAdd(&cursor[bv[i]], 1);
            sw0[lpos] = w0v[i]; sw1[lpos] = w1v[i]; sw2[lpos] = w2v[i];
        }
    }
    __syncthreads();

    // phase 4: flush bucket runs to fixed-stride global regions (semi-coalesced)
    for (int s = tid; s < nval; s += 1024) {
        unsigned u0 = sw0[s];
        int bb = (int)(u0 >> 24);                // (row>>16... row>>8)高 bits
        bb = (int)((u0 >> 16) >> 8);
        int gpos = gbase[bb] + (s - scn[bb]);
        if (gpos < CAPB) {
            rec16[(size_t)bb * CAPB + gpos] = make_uint4(u0, sw1[s], sw2[s], 0);
        } else {
            int op = atomicAdd(ovf_cnt, 1);
            if (op < OVF_CAP)
                ovf[op] = make_uint4(u0 & 0xffffu, sw1[s], sw2[s], u0 >> 16);
        }
    }
}

// ---------- Pass B: per-bucket fine sort (row&255) -> CSR + compact ----------
// Zero global atomics; all global writes coalesced.
__global__ __launch_bounds__(1024) void binB_kernel(
        const uint4* __restrict__ rec16, const int* __restrict__ bucketCnt,
        uint2* __restrict__ out8, int* __restrict__ rowStart,
        int* __restrict__ rowCnt) {
    __shared__ uint2 ostage[CAPB];                          // 40KB
    __shared__ int hist[256], scn[256], cursor[256];
    int b = blockIdx.x, tid = threadIdx.x;
    int cntb = min(bucketCnt[b], CAPB);

    if (tid < 256) hist[tid] = 0;
    __syncthreads();
    for (int i = tid; i < cntb; i += 1024) {
        unsigned u0 = rec16[(size_t)b * CAPB + i].x;
        atomicAdd(&hist[(u0 >> 16) & 255u], 1);
    }
    __syncthreads();
    if (tid < 256) scn[tid] = hist[tid];
    __syncthreads();
    for (int d = 1; d < 256; d <<= 1) {
        int v = 0;
        if (tid < 256 && tid >= d) v = scn[tid - d];
        __syncthreads();
        if (tid < 256 && tid >= d) scn[tid] += v;
        __syncthreads();
    }
    if (tid < 256) {
        int ex = scn[tid] - hist[tid];
        scn[tid] = ex;
        cursor[tid] = ex;
        rowStart[b * 256 + tid] = b * CAPB + ex;            // CSR (fixed-stride)
        rowCnt[b * 256 + tid] = hist[tid];
    }
    __syncthreads();
    for (int i = tid; i < cntb; i += 1024) {
        uint4 r = rec16[(size_t)b * CAPB + i];              // L2-hot re-read
        int rl = (int)((r.x >> 16) & 255u);
        int pos = atomicAdd(&cursor[rl], 1);
        ostage[pos] = make_uint2((r.x & 0xffffu) | (r.y << 16),
                                 (r.y >> 16) | (r.z << 16));
    }
    __syncthreads();
    for (int i = tid; i < cntb; i += 1024)
        out8[(size_t)b * CAPB + i] = ostage[i];             // coalesced flush
}

// ---------- K2: fused CSR aggregate + MFMA gemm ----------
__device__ __forceinline__ void edge_fma(uint2 rc, const unsigned* __restrict__ xb2, int lane,
        float& a0l, float& a0h, float& a1l, float& a1h, float& a2l, float& a2h) {
    int c = rc.x & 0xffffu;
    float t0 = __half2float(__ushort_as_half((unsigned short)(rc.x >> 16)));
    float t1 = __half2float(__ushort_as_half((unsigned short)(rc.y & 0xffffu)));
    float t2 = __half2float(__ushort_as_half((unsigned short)(rc.y >> 16)));
    unsigned u = xb2[(size_t)c * 64 + lane];
    float xl = __uint_as_float(u << 16), xh = __uint_as_float(u & 0xffff0000u);
    a0l = fmaf(t0, xl, a0l); a0h = fmaf(t0, xh, a0h);
    a1l = fmaf(t1, xl, a1l); a1h = fmaf(t1, xh, a1h);
    a2l = fmaf(t2, xl, a2l); a2h = fmaf(t2, xh, a2h);
}

__global__ __launch_bounds__(256) void fused_kernel(const uint2* __restrict__ out8,
        const int* __restrict__ rowStart, const int* __restrict__ rowCnt,
        const unsigned* __restrict__ xb2, const bf16x8* __restrict__ wbf,
        const float* __restrict__ bias, float* __restrict__ out, int n) {
    __shared__ short zs16[RPB][ZPAD];
    __shared__ uint2 qflat[QF];
    __shared__ int rs[RPB], rc[RPB];
    int tid = threadIdx.x;
    int lane = tid & 63, wv = tid >> 6;
    int n0 = blockIdx.x * RPB;   // 16-row tile; 16 | 256 so one coarse bucket

    if (tid < RPB) {
        int r = n0 + tid;
        rs[tid] = (r < n) ? rowStart[r] : 0;
        rc[tid] = (r < n) ? rowCnt[r] : 0;
    }
    __syncthreads();
    int base = rs[0];
    int tot = rs[RPB - 1] + rc[RPB - 1] - base;   // contiguous CSR range

    float A[4][6];
#pragma unroll
    for (int ii = 0; ii < 4; ++ii)
#pragma unroll
        for (int j = 0; j < 6; ++j) A[ii][j] = 0.f;

    for (int c0 = 0; c0 < tot; c0 += QF) {
        int cl = min(QF, tot - c0);
        __syncthreads();
        for (int i = tid; i < cl; i += 256) qflat[i] = out8[(size_t)base + c0 + i];
        __syncthreads();
#pragma unroll
        for (int ii = 0; ii < 4; ++ii) {
            int rl = wv * 4 + ii;
            int s = rs[rl] - base, e = s + rc[rl];
            int lo = max(s, c0), hi = min(e, c0 + cl);
            int p = lo;
            for (; p + 4 <= hi; p += 4) {
                uint2 r0 = qflat[p - c0], r1 = qflat[p - c0 + 1];
                uint2 r2 = qflat[p - c0 + 2], r3 = qflat[p - c0 + 3];
                edge_fma(r0, xb2, lane, A[ii][0], A[ii][1], A[ii][2], A[ii][3], A[ii][4], A[ii][5]);
                edge_fma(r1, xb2, lane, A[ii][0], A[ii][1], A[ii][2], A[ii][3], A[ii][4], A[ii][5]);
                edge_fma(r2, xb2, lane, A[ii][0], A[ii][1], A[ii][2], A[ii][3], A[ii][4], A[ii][5]);
                edge_fma(r3, xb2, lane, A[ii][0], A[ii][1], A[ii][2], A[ii][3], A[ii][4], A[ii][5]);
            }
            for (; p < hi; ++p)
                edge_fma(qflat[p - c0], xb2, lane, A[ii][0], A[ii][1], A[ii][2], A[ii][3], A[ii][4], A[ii][5]);
        }
    }

#pragma unroll
    for (int ii = 0; ii < 4; ++ii) {
        int rl = wv * 4 + ii;
        *(unsigned*)&zs16[rl][0 * DIM + 2 * lane] = pkbf(A[ii][0], A[ii][1]);
        *(unsigned*)&zs16[rl][1 * DIM + 2 * lane] = pkbf(A[ii][2], A[ii][3]);
        *(unsigned*)&zs16[rl][2 * DIM + 2 * lane] = pkbf(A[ii][4], A[ii][5]);
    }
    __syncthreads();

    // MFMA: M=16 rows, N=128 (2 x 16-tiles per wave), K=384 (12 steps)
    int quad = lane >> 4, m = lane & 15;
    int nt0 = wv * 2, nt1 = wv * 2 + 1;
    f32x4 acc0 = {0.f, 0.f, 0.f, 0.f}, acc1 = {0.f, 0.f, 0.f, 0.f};
#pragma unroll
    for (int kt = 0; kt < 12; ++kt) {
        bf16x8 a  = *(const bf16x8*)&zs16[m][kt * 32 + quad * 8];
        bf16x8 b0 = wbf[(kt * 8 + nt0) * 64 + lane];
        bf16x8 b1 = wbf[(kt * 8 + nt1) * 64 + lane];
        acc0 = __builtin_amdgcn_mfma_f32_16x16x32_bf16(a, b0, acc0, 0, 0, 0);
        acc1 = __builtin_amdgcn_mfma_f32_16x16x32_bf16(a, b1, acc1, 0, 0, 0);
    }
    // C/D layout: col(n)=lane&15, row(m)=quad*4+reg  [m89-verified]
    float bi0 = bias[nt0 * 16 + m], bi1 = bias[nt1 * 16 + m];
#pragma unroll
    for (int rr = 0; rr < 4; ++rr) {
        int node = n0 + quad * 4 + rr;
        if (node < n) {
            out[(size_t)node * DIM + nt0 * 16 + m] = acc0[rr] + bi0;
            out[(size_t)node * DIM + nt1 * 16 + m] = acc1[rr] + bi1;
        }
    }
}

// ---------- K3: exact replay of overflow edges (expected: none) ----------
__global__ __launch_bounds__(128) void ovf_kernel(const uint4* __restrict__ ovf,
        const int* __restrict__ ovf_cnt, const float* __restrict__ x,
        const float* __restrict__ w, float* __restrict__ out) {
    int total = min(*ovf_cnt, OVF_CAP);
    int d = threadIdx.x;
    for (int i = blockIdx.x; i < total; i += gridDim.x) {
        uint4 r = ovf[i];
        int col = (int)r.x, row = (int)r.w;
        float t0 = __half2float(__ushort_as_half((unsigned short)(r.y & 0xffffu)));
        float t1 = __half2float(__ushort_as_half((unsigned short)(r.y >> 16)));
        float t2 = __half2float(__ushort_as_half((unsigned short)(r.z & 0xffffu)));
        float acc = 0.f;
        for (int ii = 0; ii < DIM; ++ii) {
            const float* wp = &w[((size_t)ii * DIM + d) * KK];
            acc = fmaf(x[(size_t)col * DIM + ii],
                       t0 * wp[0] + t1 * wp[1] + t2 * wp[2], acc);
        }
        atomicAdd(&out[(size_t)row * DIM + d], acc);
    }
}

extern "C" void kernel_launch(void* const* d_in, const int* in_sizes, int n_in,
                              void* d_out, int out_size, void* d_ws, size_t ws_size,
                              hipStream_t stream) {
    const float* x    = (const float*)d_in[0];
    const float* TT   = (const float*)d_in[1];
    const float* w    = (const float*)d_in[2];
    const float* bias = (const float*)d_in[3];
    const int*   eidx = (const int*)d_in[4];
    float* out = (float*)d_out;

    int n = in_sizes[0] / DIM;     // 50000 (< 65536: row/col pack in 16 bits)
    int E = in_sizes[1] / KK;      // 800000
    int nbkt = (n + 255) >> 8;     // 196 coarse buckets

    char* ws = (char*)d_ws;
    size_t o = 0;
    auto take = [&](size_t b) { void* p = ws + o; o += (b + 255) & ~(size_t)255; return p; };
    uint4*    rec16 = (uint4*)take((size_t)nbkt * CAPB * 16);   // 16.1 MB
    uint2*    out8  = (uint2*)take((size_t)nbkt * CAPB * 8);    //  8.0 MB
    int*      rowStart = (int*)take((size_t)nbkt * 256 * 4);    //  200 KB
    int*      rowCnt   = (int*)take((size_t)nbkt * 256 * 4);    //  200 KB
    int*      bcnt  = (int*)take((size_t)(NBKT + 64) * 4);      // bucketCnt+ovf_cnt
    uint4*    ovf   = (uint4*)take((size_t)OVF_CAP * 16);       //  1 MB
    bf16x8*   wbf   = (bf16x8*)take((size_t)12 * 8 * 64 * 16);  //  786 KB
    unsigned* xb2   = (unsigned*)take((size_t)n * DIM * 2);     // 12.8 MB
    (void)ws_size;
    int* ovf_cnt = bcnt + NBKT;

    hipMemsetAsync(bcnt, 0, (size_t)(NBKT + 64) * 4, stream);   // 1.3 KB only

    int xq = n * DIM / 4;
    int xblk = (xq + 255) / 256;          // 6250
    int ablk = (E + EBLK - 1) / EBLK;     // 196

    k1a_kernel<<<xblk + 24, 256, 0, stream>>>(x, w, (uint2*)xb2, wbf, xq, xblk);
    binA_kernel<<<ablk, 1024, 0, stream>>>(TT, eidx, bcnt, rec16, ovf_cnt, ovf, E);
    binB_kernel<<<nbkt, 1024, 0, stream>>>(rec16, bcnt, out8, rowStart, rowCnt);
    fused_kernel<<<(n + RPB - 1) / RPB, 256, 0, stream>>>(
        out8, rowStart, rowCnt, xb2, wbf, bias, out, n);
    ovf_kernel<<<64, 128, 0, stream>>>(ovf, ovf_cnt, x, w, out);
}